// Round 2
// baseline (70.462 us; speedup 1.0000x reference)
//
#include <hip/hip_runtime.h>

#define B_ 32
#define N_ 256
#define C_ 512
#define O_ 512
#define S_ 512

typedef __attribute__((ext_vector_type(8))) short short8;
typedef __attribute__((ext_vector_type(4))) float f32x4;

__device__ __forceinline__ short f2bf(float f) {
    union { float f; unsigned u; } v; v.f = f;
    unsigned r = v.u + 0x7fffu + ((v.u >> 16) & 1u);  // RNE (no NaN handling; inputs are finite)
    return (short)(r >> 16);
}

// ---------------- Kernel 1: s_map[n][b] = gain * dot(s[b,:], s_w[n,:]) + s_b[n]
__global__ __launch_bounds__(256) void smap_kernel(const float* __restrict__ s,
                                                   const float* __restrict__ s_w,
                                                   const float* __restrict__ s_b,
                                                   float* __restrict__ smap) {
    int w = blockIdx.x * 4 + (threadIdx.x >> 6);   // 8192 waves, one per (b,n)
    int lane = threadIdx.x & 63;
    int b = w >> 8;        // / N_
    int n = w & (N_ - 1);
    float sum = 0.f;
#pragma unroll
    for (int j = 0; j < 8; ++j) {
        int c = lane + 64 * j;
        sum += s[b * S_ + c] * s_w[n * S_ + c];
    }
#pragma unroll
    for (int off = 32; off; off >>= 1) sum += __shfl_xor(sum, off, 64);
    if (lane == 0) smap[n * B_ + b] = sum * 0.04419417382415922f + s_b[n];  // 1/sqrt(512)
}

// ---------------- Kernel 2: fused GEMM + sumsq + demod epilogue
// block = 256 thr (4 waves); blockIdx -> (n, o-tile of 128); wave -> 32-wide o-sub.
// out[b][n][o] = smap[b,n]*raw*rsqrt(smap^2*ssq[n,o]+1e-8) + bias[n,o]
__global__ __launch_bounds__(256) void tml_kernel(const float* __restrict__ x,
                                                  const float* __restrict__ weight,
                                                  const float* __restrict__ bias,
                                                  const float* __restrict__ smap,
                                                  float* __restrict__ out) {
    const int bid  = blockIdx.x;
    const int n    = bid >> 2;
    const int ot   = bid & 3;
    const int tid  = threadIdx.x;
    const int wv   = tid >> 6;
    const int lane = tid & 63;
    const int l16  = lane & 15;
    const int lk   = lane >> 4;   // 0..3 -> k-group

    __shared__ short xs[B_][C_ + 8];   // bf16 bits, +8 pad kills bank conflicts
    __shared__ float sm_lds[B_];

    // ---- stage x[:, n, :] -> bf16 LDS (4096 float4 loads, coalesced)
    const float* xn = x + (size_t)n * C_;
#pragma unroll
    for (int r = 0; r < 16; ++r) {
        int i  = r * 256 + tid;
        int b  = i >> 7;             // 128 float4 per row
        int c4 = (i & 127) << 2;
        const float4 v = *(const float4*)(xn + (size_t)b * (N_ * C_) + c4);
        short4 h;
        h.x = f2bf(v.x); h.y = f2bf(v.y); h.z = f2bf(v.z); h.w = f2bf(v.w);
        *(short4*)&xs[b][c4] = h;
    }
    if (tid < B_) sm_lds[tid] = smap[n * B_ + tid];
    __syncthreads();

    const int ob = ot * 128 + wv * 32;                 // wave's o base (32 wide)
    const float* wrow = weight + (size_t)n * (O_ * C_) + (size_t)(ob + l16) * C_;

    f32x4 acc00 = {0.f,0.f,0.f,0.f}, acc01 = acc00, acc10 = acc00, acc11 = acc00;
    float ssq0 = 0.f, ssq1 = 0.f;

#pragma unroll 2
    for (int cb = 0; cb < C_; cb += 32) {
        const int co = cb + lk * 8;                    // this lane's k-slice (8 consecutive c)
        // A frags from LDS (bf16, 16B reads)
        short8 a0 = *(const short8*)&xs[l16][co];
        short8 a1 = *(const short8*)&xs[16 + l16][co];
        // B frags from global fp32 (each (o,c) touched by exactly one lane once)
        float4 w00 = *(const float4*)(wrow + co);
        float4 w01 = *(const float4*)(wrow + co + 4);
        float4 w10 = *(const float4*)(wrow + 16 * C_ + co);
        float4 w11 = *(const float4*)(wrow + 16 * C_ + co + 4);

        ssq0 += w00.x*w00.x + w00.y*w00.y + w00.z*w00.z + w00.w*w00.w
              + w01.x*w01.x + w01.y*w01.y + w01.z*w01.z + w01.w*w01.w;
        ssq1 += w10.x*w10.x + w10.y*w10.y + w10.z*w10.z + w10.w*w10.w
              + w11.x*w11.x + w11.y*w11.y + w11.z*w11.z + w11.w*w11.w;

        short8 b0, b1;
        b0[0]=f2bf(w00.x); b0[1]=f2bf(w00.y); b0[2]=f2bf(w00.z); b0[3]=f2bf(w00.w);
        b0[4]=f2bf(w01.x); b0[5]=f2bf(w01.y); b0[6]=f2bf(w01.z); b0[7]=f2bf(w01.w);
        b1[0]=f2bf(w10.x); b1[1]=f2bf(w10.y); b1[2]=f2bf(w10.z); b1[3]=f2bf(w10.w);
        b1[4]=f2bf(w11.x); b1[5]=f2bf(w11.y); b1[6]=f2bf(w11.z); b1[7]=f2bf(w11.w);

        acc00 = __builtin_amdgcn_mfma_f32_16x16x32_bf16(a0, b0, acc00, 0, 0, 0);
        acc10 = __builtin_amdgcn_mfma_f32_16x16x32_bf16(a1, b0, acc10, 0, 0, 0);
        acc01 = __builtin_amdgcn_mfma_f32_16x16x32_bf16(a0, b1, acc01, 0, 0, 0);
        acc11 = __builtin_amdgcn_mfma_f32_16x16x32_bf16(a1, b1, acc11, 0, 0, 0);
    }

    // ssq currently partial per k-group; reduce over lanes with same l16 (xor 16, 32)
    ssq0 += __shfl_xor(ssq0, 16, 64);  ssq0 += __shfl_xor(ssq0, 32, 64);
    ssq1 += __shfl_xor(ssq1, 16, 64);  ssq1 += __shfl_xor(ssq1, 32, 64);

    // ---- epilogue. C/D layout: col = lane&15, row = (lane>>4)*4 + reg
#pragma unroll
    for (int f = 0; f < 2; ++f) {
        const int o  = ob + f * 16 + l16;
        const float bv = bias[n * O_ + o];
        const float sq = f ? ssq1 : ssq0;
        const f32x4 am0 = f ? acc01 : acc00;
        const f32x4 am1 = f ? acc11 : acc10;
#pragma unroll
        for (int r = 0; r < 4; ++r) {
            {   // m-frag 0: rows 0..15
                const int brow = lk * 4 + r;
                const float smv = sm_lds[brow];
                const float dec = rsqrtf(smv * smv * sq + 1e-8f);
                out[(size_t)brow * (N_ * O_) + n * O_ + o] = am0[r] * smv * dec + bv;
            }
            {   // m-frag 1: rows 16..31
                const int brow = 16 + lk * 4 + r;
                const float smv = sm_lds[brow];
                const float dec = rsqrtf(smv * smv * sq + 1e-8f);
                out[(size_t)brow * (N_ * O_) + n * O_ + o] = am1[r] * smv * dec + bv;
            }
        }
    }
}

extern "C" void kernel_launch(void* const* d_in, const int* in_sizes, int n_in,
                              void* d_out, int out_size, void* d_ws, size_t ws_size,
                              hipStream_t stream) {
    const float* x      = (const float*)d_in[0];
    const float* s      = (const float*)d_in[1];
    const float* weight = (const float*)d_in[2];
    const float* bias   = (const float*)d_in[3];
    const float* s_w    = (const float*)d_in[4];
    const float* s_b    = (const float*)d_in[5];
    float* out  = (float*)d_out;
    float* smap = (float*)d_ws;   // B_*N_ floats = 32 KiB

    smap_kernel<<<(B_ * N_) / 4, 256, 0, stream>>>(s, s_w, s_b, smap);
    tml_kernel<<<N_ * 4, 256, 0, stream>>>(x, weight, bias, smap, out);
}

// Round 3
// 66.299 us; speedup vs baseline: 1.0628x; 1.0628x over previous
//
#include <hip/hip_runtime.h>

#define B_ 32
#define N_ 256
#define C_ 512
#define O_ 512
#define S_ 512

typedef __attribute__((ext_vector_type(8))) short short8;
typedef __attribute__((ext_vector_type(4))) float f32x4;

__device__ __forceinline__ short f2bf(float f) {
    union { float f; unsigned u; } v; v.f = f;
    unsigned r = v.u + 0x7fffu + ((v.u >> 16) & 1u);  // RNE (inputs finite)
    return (short)(r >> 16);
}

// Fused: smap GEMV + modulated GEMM + sumsq + demod epilogue, one kernel.
// grid = 1024 hw blocks; XCD-swizzled so the 4 o-tiles of one n share an XCD's L2.
// block = 256 thr (4 waves); wave -> 32-wide o-sub of a 128-wide o-tile.
__global__ __launch_bounds__(256) void tml_kernel(const float* __restrict__ x,
                                                  const float* __restrict__ s,
                                                  const float* __restrict__ weight,
                                                  const float* __restrict__ bias,
                                                  const float* __restrict__ s_w,
                                                  const float* __restrict__ s_b,
                                                  float* __restrict__ out) {
    // ---- XCD-aware bijective remap (nwg=1024, 8 XCDs, dispatch h -> XCD h%8)
    const int h       = blockIdx.x;
    const int logical = (h & 7) * 128 + (h >> 3);
    const int n       = logical >> 2;
    const int ot      = logical & 3;

    const int tid  = threadIdx.x;
    const int wv   = tid >> 6;
    const int lane = tid & 63;
    const int l16  = lane & 15;
    const int lk   = lane >> 4;   // 0..3 -> k-group

    __shared__ short xs[B_][C_ + 8];   // bf16 bits, +8 pad kills bank conflicts
    __shared__ float sm_lds[B_];

    // ---- fused smap: sm_lds[b] = gain * dot(s[b,:], s_w[n,:]) + s_b[n]
    {
        const int b    = tid >> 3;        // 0..31
        const int slot = tid & 7;         // 8 threads per b, same-wave lanes
        const float* sp = s   + (size_t)b * S_ + slot * 64;
        const float* wp = s_w + (size_t)n * S_ + slot * 64;   // broadcast across b
        float sum = 0.f;
#pragma unroll
        for (int j = 0; j < 16; ++j) {
            float4 sv = *(const float4*)(sp + 4 * j);
            float4 wv4 = *(const float4*)(wp + 4 * j);
            sum += sv.x * wv4.x + sv.y * wv4.y + sv.z * wv4.z + sv.w * wv4.w;
        }
        sum += __shfl_xor(sum, 1, 64);
        sum += __shfl_xor(sum, 2, 64);
        sum += __shfl_xor(sum, 4, 64);
        if (slot == 0) sm_lds[b] = sum * 0.04419417382415922f + s_b[n];  // 1/sqrt(512)
    }

    // ---- stage x[:, n, :] -> bf16 LDS (coalesced float4; L2-shared across the 4 same-n blocks)
    const float* xn = x + (size_t)n * C_;
#pragma unroll
    for (int r = 0; r < 16; ++r) {
        int i  = r * 256 + tid;
        int b  = i >> 7;             // 128 float4 per row
        int c4 = (i & 127) << 2;
        const float4 v = *(const float4*)(xn + (size_t)b * (N_ * C_) + c4);
        short4 hh;
        hh.x = f2bf(v.x); hh.y = f2bf(v.y); hh.z = f2bf(v.z); hh.w = f2bf(v.w);
        *(short4*)&xs[b][c4] = hh;
    }
    __syncthreads();

    const int ob = ot * 128 + wv * 32;                 // wave's o base (32 wide)
    const float* wrow = weight + (size_t)n * (O_ * C_) + (size_t)(ob + l16) * C_;

    f32x4 acc00 = {0.f,0.f,0.f,0.f}, acc01 = acc00, acc10 = acc00, acc11 = acc00;
    float ssq0 = 0.f, ssq1 = 0.f;

#pragma unroll 2
    for (int cb = 0; cb < C_; cb += 32) {
        const int co = cb + lk * 8;                    // this lane's k-slice (8 consecutive c)
        // A frags from LDS (bf16, 16B reads)
        short8 a0 = *(const short8*)&xs[l16][co];
        short8 a1 = *(const short8*)&xs[16 + l16][co];
        // B frags from global fp32 (each (o,c) touched by exactly one lane once)
        float4 w00 = *(const float4*)(wrow + co);
        float4 w01 = *(const float4*)(wrow + co + 4);
        float4 w10 = *(const float4*)(wrow + 16 * C_ + co);
        float4 w11 = *(const float4*)(wrow + 16 * C_ + co + 4);

        ssq0 += w00.x*w00.x + w00.y*w00.y + w00.z*w00.z + w00.w*w00.w
              + w01.x*w01.x + w01.y*w01.y + w01.z*w01.z + w01.w*w01.w;
        ssq1 += w10.x*w10.x + w10.y*w10.y + w10.z*w10.z + w10.w*w10.w
              + w11.x*w11.x + w11.y*w11.y + w11.z*w11.z + w11.w*w11.w;

        short8 b0, b1;
        b0[0]=f2bf(w00.x); b0[1]=f2bf(w00.y); b0[2]=f2bf(w00.z); b0[3]=f2bf(w00.w);
        b0[4]=f2bf(w01.x); b0[5]=f2bf(w01.y); b0[6]=f2bf(w01.z); b0[7]=f2bf(w01.w);
        b1[0]=f2bf(w10.x); b1[1]=f2bf(w10.y); b1[2]=f2bf(w10.z); b1[3]=f2bf(w10.w);
        b1[4]=f2bf(w11.x); b1[5]=f2bf(w11.y); b1[6]=f2bf(w11.z); b1[7]=f2bf(w11.w);

        acc00 = __builtin_amdgcn_mfma_f32_16x16x32_bf16(a0, b0, acc00, 0, 0, 0);
        acc10 = __builtin_amdgcn_mfma_f32_16x16x32_bf16(a1, b0, acc10, 0, 0, 0);
        acc01 = __builtin_amdgcn_mfma_f32_16x16x32_bf16(a0, b1, acc01, 0, 0, 0);
        acc11 = __builtin_amdgcn_mfma_f32_16x16x32_bf16(a1, b1, acc11, 0, 0, 0);
    }

    // ssq is partial per k-group; reduce over lanes with same l16 (xor 16, 32)
    ssq0 += __shfl_xor(ssq0, 16, 64);  ssq0 += __shfl_xor(ssq0, 32, 64);
    ssq1 += __shfl_xor(ssq1, 16, 64);  ssq1 += __shfl_xor(ssq1, 32, 64);

    // ---- epilogue. C/D layout: col = lane&15, row = (lane>>4)*4 + reg
#pragma unroll
    for (int f = 0; f < 2; ++f) {
        const int o  = ob + f * 16 + l16;
        const float bv = bias[n * O_ + o];
        const float sq = f ? ssq1 : ssq0;
        const f32x4 am0 = f ? acc01 : acc00;
        const f32x4 am1 = f ? acc11 : acc10;
#pragma unroll
        for (int r = 0; r < 4; ++r) {
            {   // m-frag 0: rows 0..15
                const int brow = lk * 4 + r;
                const float smv = sm_lds[brow];
                const float dec = rsqrtf(smv * smv * sq + 1e-8f);
                out[(size_t)brow * (N_ * O_) + n * O_ + o] = am0[r] * smv * dec + bv;
            }
            {   // m-frag 1: rows 16..31
                const int brow = 16 + lk * 4 + r;
                const float smv = sm_lds[brow];
                const float dec = rsqrtf(smv * smv * sq + 1e-8f);
                out[(size_t)brow * (N_ * O_) + n * O_ + o] = am1[r] * smv * dec + bv;
            }
        }
    }
}

extern "C" void kernel_launch(void* const* d_in, const int* in_sizes, int n_in,
                              void* d_out, int out_size, void* d_ws, size_t ws_size,
                              hipStream_t stream) {
    const float* x      = (const float*)d_in[0];
    const float* s      = (const float*)d_in[1];
    const float* weight = (const float*)d_in[2];
    const float* bias   = (const float*)d_in[3];
    const float* s_w    = (const float*)d_in[4];
    const float* s_b    = (const float*)d_in[5];
    float* out = (float*)d_out;

    tml_kernel<<<N_ * 4, 256, 0, stream>>>(x, s, weight, bias, s_w, s_b, out);
}

// Round 4
// 63.159 us; speedup vs baseline: 1.1156x; 1.0497x over previous
//
#include <hip/hip_runtime.h>

#define B_ 32
#define N_ 256
#define C_ 512
#define O_ 512
#define S_ 512

#define KT  64                // weight k-tile (floats)
#define NKT (C_ / KT)         // 8 tiles
#define WST 72                // wt row stride in shorts: 144 B, 16B-aligned, odd-ish banks

typedef __attribute__((ext_vector_type(8))) short short8;
typedef __attribute__((ext_vector_type(4))) float f32x4;

__device__ __forceinline__ short f2bf(float f) {
    union { float f; unsigned u; } v; v.f = f;
    unsigned r = v.u + 0x7fffu + ((v.u >> 16) & 1u);  // RNE (inputs finite)
    return (short)(r >> 16);
}
__device__ __forceinline__ float bf2f(short s) {
    union { unsigned u; float f; } v; v.u = ((unsigned)(unsigned short)s) << 16;
    return v.f;
}

// Fused smap + modulated GEMM + sumsq + demod. Weight streamed via LDS so
// global reads are 256B-contiguous per row (4 segments/instr instead of 16-32).
__global__ __launch_bounds__(256, 2) void tml_kernel(const float* __restrict__ x,
                                                     const float* __restrict__ s,
                                                     const float* __restrict__ weight,
                                                     const float* __restrict__ bias,
                                                     const float* __restrict__ s_w,
                                                     const float* __restrict__ s_b,
                                                     float* __restrict__ out) {
    // XCD-aware bijective remap (nwg=1024 divisible by 8)
    const int h       = blockIdx.x;
    const int logical = (h & 7) * 128 + (h >> 3);
    const int n       = logical >> 2;
    const int ot      = logical & 3;

    const int tid  = threadIdx.x;
    const int wv   = tid >> 6;
    const int lane = tid & 63;
    const int l16  = lane & 15;
    const int lk   = lane >> 4;

    __shared__ short xs[B_][C_ + 8];        // bf16 x, stride 520 (conflict-safe)
    __shared__ short wt[2][128][WST];       // bf16 weight k-tiles, double-buffered
    __shared__ float sm_lds[B_];

    // ---- weight staging map: 16 consecutive threads cover one row's 256 B k-slice
    const int srow = tid >> 4;   // 0..15 (row within 16-row group)
    const int scol = tid & 15;   // 16 B slot (4 floats)
    const float* wbase = weight + (size_t)n * (O_ * C_) + (size_t)(ot * 128) * C_ + scol * 4;

    float4 rg0[8], rg1[8];
    // issue tile 0 loads now; latency hides under smap + x staging
#pragma unroll
    for (int i = 0; i < 8; ++i)
        rg0[i] = *(const float4*)(wbase + (size_t)(i * 16 + srow) * C_);

    // ---- fused smap: sm_lds[b] = gain * dot(s[b,:], s_w[n,:]) + s_b[n]
    {
        const int b    = tid >> 3;
        const int slot = tid & 7;
        const float* sp = s   + (size_t)b * S_ + slot * 64;
        const float* wp = s_w + (size_t)n * S_ + slot * 64;
        float sum = 0.f;
#pragma unroll
        for (int j = 0; j < 16; ++j) {
            float4 sv  = *(const float4*)(sp + 4 * j);
            float4 wv4 = *(const float4*)(wp + 4 * j);
            sum += sv.x * wv4.x + sv.y * wv4.y + sv.z * wv4.z + sv.w * wv4.w;
        }
        sum += __shfl_xor(sum, 1, 64);
        sum += __shfl_xor(sum, 2, 64);
        sum += __shfl_xor(sum, 4, 64);
        if (slot == 0) sm_lds[b] = sum * 0.04419417382415922f + s_b[n];
    }

    // ---- stage x[:, n, :] -> bf16 LDS
    const float* xn = x + (size_t)n * C_;
#pragma unroll
    for (int r = 0; r < 16; ++r) {
        int i  = r * 256 + tid;
        int b  = i >> 7;
        int c4 = (i & 127) << 2;
        const float4 v = *(const float4*)(xn + (size_t)b * (N_ * C_) + c4);
        short4 hh;
        hh.x = f2bf(v.x); hh.y = f2bf(v.y); hh.z = f2bf(v.z); hh.w = f2bf(v.w);
        *(short4*)&xs[b][c4] = hh;
    }

    f32x4 acc00 = {0.f,0.f,0.f,0.f}, acc01 = acc00, acc10 = acc00, acc11 = acc00;
    float ssq0 = 0.f, ssq1 = 0.f;

    // One K-step: prefetch next tile, commit current regs->LDS, barrier, MFMA.
    // Single barrier per tile is safe under double-buffering (buffer pb is
    // rewritten only two tiles later, with a barrier in between).
#define STEP(T, RCUR, RNXT, PB)                                                   \
    {                                                                             \
        if ((T) + 1 < NKT) {                                                      \
            _Pragma("unroll")                                                     \
            for (int i = 0; i < 8; ++i)                                           \
                RNXT[i] = *(const float4*)(wbase + (size_t)(i * 16 + srow) * C_   \
                                           + ((T) + 1) * KT);                     \
        }                                                                         \
        _Pragma("unroll")                                                         \
        for (int i = 0; i < 8; ++i) {                                             \
            short4 hv;                                                            \
            hv.x = f2bf(RCUR[i].x); hv.y = f2bf(RCUR[i].y);                       \
            hv.z = f2bf(RCUR[i].z); hv.w = f2bf(RCUR[i].w);                       \
            *(short4*)&wt[PB][i * 16 + srow][scol * 4] = hv;                      \
        }                                                                         \
        __syncthreads();                                                          \
        _Pragma("unroll")                                                         \
        for (int ks = 0; ks < KT / 32; ++ks) {                                    \
            const int co = ks * 32 + lk * 8;                                      \
            short8 a0 = *(const short8*)&xs[l16][(T) * KT + co];                  \
            short8 a1 = *(const short8*)&xs[16 + l16][(T) * KT + co];             \
            short8 b0 = *(const short8*)&wt[PB][wv * 32 + l16][co];               \
            short8 b1 = *(const short8*)&wt[PB][wv * 32 + 16 + l16][co];          \
            _Pragma("unroll")                                                     \
            for (int j = 0; j < 8; ++j) {                                         \
                float f0 = bf2f(b0[j]), f1 = bf2f(b1[j]);                         \
                ssq0 += f0 * f0; ssq1 += f1 * f1;                                 \
            }                                                                     \
            acc00 = __builtin_amdgcn_mfma_f32_16x16x32_bf16(a0, b0, acc00, 0,0,0);\
            acc10 = __builtin_amdgcn_mfma_f32_16x16x32_bf16(a1, b0, acc10, 0,0,0);\
            acc01 = __builtin_amdgcn_mfma_f32_16x16x32_bf16(a0, b1, acc01, 0,0,0);\
            acc11 = __builtin_amdgcn_mfma_f32_16x16x32_bf16(a1, b1, acc11, 0,0,0);\
        }                                                                         \
    }

    STEP(0, rg0, rg1, 0)
    STEP(1, rg1, rg0, 1)
    STEP(2, rg0, rg1, 0)
    STEP(3, rg1, rg0, 1)
    STEP(4, rg0, rg1, 0)
    STEP(5, rg1, rg0, 1)
    STEP(6, rg0, rg1, 0)
    STEP(7, rg1, rg0, 1)
#undef STEP

    // ssq partial per k-group; reduce over lk (xor 16, 32)
    ssq0 += __shfl_xor(ssq0, 16, 64);  ssq0 += __shfl_xor(ssq0, 32, 64);
    ssq1 += __shfl_xor(ssq1, 16, 64);  ssq1 += __shfl_xor(ssq1, 32, 64);

    // ---- epilogue. C/D layout: col = lane&15, row = (lane>>4)*4 + reg
    const int ob = ot * 128 + wv * 32;
#pragma unroll
    for (int f = 0; f < 2; ++f) {
        const int o  = ob + f * 16 + l16;
        const float bv = bias[n * O_ + o];
        const float sq = f ? ssq1 : ssq0;
        const f32x4 am0 = f ? acc01 : acc00;
        const f32x4 am1 = f ? acc11 : acc10;
#pragma unroll
        for (int r = 0; r < 4; ++r) {
            {
                const int brow = lk * 4 + r;
                const float smv = sm_lds[brow];
                const float dec = rsqrtf(smv * smv * sq + 1e-8f);
                out[(size_t)brow * (N_ * O_) + n * O_ + o] = am0[r] * smv * dec + bv;
            }
            {
                const int brow = 16 + lk * 4 + r;
                const float smv = sm_lds[brow];
                const float dec = rsqrtf(smv * smv * sq + 1e-8f);
                out[(size_t)brow * (N_ * O_) + n * O_ + o] = am1[r] * smv * dec + bv;
            }
        }
    }
}

extern "C" void kernel_launch(void* const* d_in, const int* in_sizes, int n_in,
                              void* d_out, int out_size, void* d_ws, size_t ws_size,
                              hipStream_t stream) {
    const float* x      = (const float*)d_in[0];
    const float* s      = (const float*)d_in[1];
    const float* weight = (const float*)d_in[2];
    const float* bias   = (const float*)d_in[3];
    const float* s_w    = (const float*)d_in[4];
    const float* s_b    = (const float*)d_in[5];
    float* out = (float*)d_out;

    tml_kernel<<<N_ * 4, 256, 0, stream>>>(x, s, weight, bias, s_w, s_b, out);
}